// Round 1
// 166.938 us; speedup vs baseline: 1.1254x; 1.1254x over previous
//
#include <hip/hip_runtime.h>
#include <math.h>

#define DEV __device__ __forceinline__

struct C2 { float x, y; };
DEV C2 cmul(C2 a, C2 b){ return {a.x*b.x - a.y*b.y, a.x*b.y + a.y*b.x}; }
DEV C2 cadd(C2 a, C2 b){ return {a.x+b.x, a.y+b.y}; }
DEV C2 cscale(C2 a, float s){ return {a.x*s, a.y*s}; }
DEV C2 cnegi(C2 a){ return {a.y, -a.x}; } // multiply by -i

// ---------------------------------------------------------------------------
// K1 (fused): per block (c,b) -> rows r = b*2048 + c*32 + j, j in [0,32).
// Wave wv owns rows wv*8 .. wv*8+7 END-TO-END (no block barrier between
// score and value phases):
//   A1: k_states via in-register Wk slice + butterfly reduce, 2 rows per
//       iteration (ILP-2) with next-pair global prefetch. ks -> wave-local LDS.
//   (value prefetch: issue this wave's 16 value float4 loads NOW — they are
//    independent of the scores; latency hides under A2.)
//   A2: ALL 8 rows' scores in ONE batch: lane=(pair p, row j) reads ks from
//       LDS, one sincos block, fold over p via shfl_xor(8|16) -> w in register.
//   B : weighted sum of own 8 value rows from registers; single barrier;
//       cross-wave 4-way LDS column reduce -> partial; per-chunk w-sum.
// ---------------------------------------------------------------------------
__global__ __launch_bounds__(256) void k_score_wsum(const float* __restrict__ key,
                                                    const float* __restrict__ Wk,
                                                    const float* __restrict__ bk,
                                                    const float* __restrict__ value,
                                                    float* __restrict__ partial,
                                                    float* __restrict__ partialw)
{
    const int c = blockIdx.x;        // 0..63
    const int b = blockIdx.y;        // 0..7
    const int t = threadIdx.x;
    const int lane = t & 63;
    const int wv   = t >> 6;         // wave 0..3
    const int base = b * 2048 + c * 32;
    const int r0   = base + wv * 8;  // this wave's first row

    __shared__ float  kslds[32][16]; // k_states staging (per-wave region)
    __shared__ float4 red[4][128];   // cross-wave column reduce
    __shared__ float  wsums[4];

    // per-lane Wk slice: rows 4l..4l+3 and 256+4l..256+4l+3, all 16 cols
    float4 wk[8][4];
    #pragma unroll
    for (int jj = 0; jj < 4; ++jj) {
        const float4* w0 = (const float4*)(Wk + (4 * lane + jj) * 16);
        const float4* w1 = (const float4*)(Wk + (256 + 4 * lane + jj) * 16);
        #pragma unroll
        for (int q = 0; q < 4; ++q) { wk[jj][q] = w0[q]; wk[4 + jj][q] = w1[q]; }
    }
    const float bkr = bk[lane & 15];
    const float c0 = 0.30901699437494745f;   // cos(pi*0.8/2)
    const float s0 = 0.9510565162951535f;    // sin(pi*0.8/2)

    // ---- Phase A1: k_states for 8 rows, 2 rows/iter + prefetch ----
    const float4* kp = (const float4*)(key + (size_t)r0 * 512);
    float4 a0 = kp[lane],       a1 = kp[64 + lane];
    float4 b0 = kp[128 + lane], b1 = kp[192 + lane];
    #pragma unroll
    for (int i = 0; i < 8; i += 2) {
        float4 na0, na1, nb0, nb1;
        if (i < 6) {
            na0 = kp[(i + 2) * 128 + lane]; na1 = kp[(i + 2) * 128 + 64 + lane];
            nb0 = kp[(i + 3) * 128 + lane]; nb1 = kp[(i + 3) * 128 + 64 + lane];
        }
        float eA[8] = {a0.x, a0.y, a0.z, a0.w, a1.x, a1.y, a1.z, a1.w};
        float eB[8] = {b0.x, b0.y, b0.z, b0.w, b1.x, b1.y, b1.z, b1.w};
        float accA[16], accB[16];
        #pragma unroll
        for (int k = 0; k < 16; ++k) { accA[k] = 0.f; accB[k] = 0.f; }
        #pragma unroll
        for (int jr = 0; jr < 8; ++jr) {
            #pragma unroll
            for (int q = 0; q < 4; ++q) {
                accA[4*q+0] = fmaf(eA[jr], wk[jr][q].x, accA[4*q+0]);
                accA[4*q+1] = fmaf(eA[jr], wk[jr][q].y, accA[4*q+1]);
                accA[4*q+2] = fmaf(eA[jr], wk[jr][q].z, accA[4*q+2]);
                accA[4*q+3] = fmaf(eA[jr], wk[jr][q].w, accA[4*q+3]);
                accB[4*q+0] = fmaf(eB[jr], wk[jr][q].x, accB[4*q+0]);
                accB[4*q+1] = fmaf(eB[jr], wk[jr][q].y, accB[4*q+1]);
                accB[4*q+2] = fmaf(eB[jr], wk[jr][q].z, accB[4*q+2]);
                accB[4*q+3] = fmaf(eB[jr], wk[jr][q].w, accB[4*q+3]);
            }
        }
        // butterfly both rows interleaved (independent chains)
        #pragma unroll
        for (int s = 0; s < 4; ++s) {
            const int m = 1 << s;
            const int bbit = (lane >> s) & 1;
            #pragma unroll
            for (int jj = 0; jj < (16 >> (s + 1)); ++jj) {
                float sA = bbit ? accA[2*jj] : accA[2*jj+1];
                float kA = bbit ? accA[2*jj+1] : accA[2*jj];
                accA[jj] = kA + __shfl_xor(sA, m);
                float sB = bbit ? accB[2*jj] : accB[2*jj+1];
                float kB = bbit ? accB[2*jj+1] : accB[2*jj];
                accB[jj] = kB + __shfl_xor(sB, m);
            }
        }
        float ksA = accA[0];
        ksA += __shfl_xor(ksA, 16); ksA += __shfl_xor(ksA, 32); ksA += bkr;
        float ksB = accB[0];
        ksB += __shfl_xor(ksB, 16); ksB += __shfl_xor(ksB, 32); ksB += bkr;
        if (lane < 16) {
            kslds[wv * 8 + i][lane]     = ksA;
            kslds[wv * 8 + i + 1][lane] = ksB;
        }
        if (i < 6) { a0 = na0; a1 = na1; b0 = nb0; b1 = nb1; }
    }

    // ---- value prefetch (independent of scores; hides under A2) ----
    const float4* vp = (const float4*)(value + (size_t)r0 * 512);
    float4 vreg[16];
    #pragma unroll
    for (int j = 0; j < 8; ++j) {
        vreg[2*j]   = vp[j * 128 + lane];
        vreg[2*j+1] = vp[j * 128 + 64 + lane];
    }

    // ---- Phase A2: batched scores for the wave's 8 rows ----
    const int p  = (lane >> 3) & 3;   // pair 0..3
    const int jr = lane & 7;          // row-in-wave 0..7
    float4 kv = *(const float4*)&kslds[wv * 8 + jr][4 * p];
    float ax = kv.x, az = kv.y, bx = kv.z, bz = kv.w;
    float cxa = 1.f, sxa = 0.f; if (ax > 0.f){ sxa = __sinf(0.5f*ax); cxa = __cosf(0.5f*ax); }
    float cpa = 1.f, spa = 0.f; if (az > 0.f){ spa = __sinf(0.5f*az); cpa = __cosf(0.5f*az); }
    float cxb = 1.f, sxb = 0.f; if (bx > 0.f){ sxb = __sinf(0.5f*bx); cxb = __cosf(0.5f*bx); }
    float cpb = 1.f, spb = 0.f; if (bz > 0.f){ spb = __sinf(0.5f*bz); cpb = __cosf(0.5f*bz); }
    C2 A00{cpa*cxa, -spa*cxa}, A01{-spa*sxa, -cpa*sxa};
    C2 A10{spa*sxa, -cpa*sxa}, A11{ cpa*cxa,  spa*cxa};
    C2 B00{cpb*cxb, -spb*cxb}, B01{-spb*sxb, -cpb*sxb};
    C2 B10{spb*sxb, -cpb*sxb}, B11{ cpb*cxb,  spb*cxb};
    C2 u = cadd(cmul(B00, cadd(A00, cscale(A01, c0))),
                cscale(cnegi(cmul(A01, B01)), s0));
    C2 v = cadd(cmul(B10, cadd(A10, cscale(A11, c0))),
                cscale(cnegi(cmul(A11, B11)), s0));
    float ps = u.x*u.x + u.y*u.y + v.x*v.x + v.y*v.y;
    ps += __shfl_xor(ps, 8);          // fold pairs (p bits at 3..4)
    ps += __shfl_xor(ps, 16);
    float w_all = __expf(ps * 0.125f); // lane holds w for row jr (all lanes)

    // wave w-sum (fold over jr bits 0..2)
    float sw = w_all;
    sw += __shfl_xor(sw, 1); sw += __shfl_xor(sw, 2); sw += __shfl_xor(sw, 4);
    if (lane == 0) wsums[wv] = sw;

    // ---- Phase B: weighted sum of own 8 value rows (from registers) ----
    float4 aA = {0.f,0.f,0.f,0.f}, aB = {0.f,0.f,0.f,0.f};
    #pragma unroll
    for (int j = 0; j < 8; ++j) {
        float wj = __shfl(w_all, j);
        float4 v0 = vreg[2*j], v1 = vreg[2*j+1];
        aA.x = fmaf(wj, v0.x, aA.x); aA.y = fmaf(wj, v0.y, aA.y);
        aA.z = fmaf(wj, v0.z, aA.z); aA.w = fmaf(wj, v0.w, aA.w);
        aB.x = fmaf(wj, v1.x, aB.x); aB.y = fmaf(wj, v1.y, aB.y);
        aB.z = fmaf(wj, v1.z, aB.z); aB.w = fmaf(wj, v1.w, aB.w);
    }
    red[wv][lane] = aA;
    red[wv][64 + lane] = aB;
    __syncthreads();
    if (t < 128) {
        float4 q0 = red[0][t], q1 = red[1][t], q2 = red[2][t], q3 = red[3][t];
        float4 o = { q0.x+q1.x+q2.x+q3.x, q0.y+q1.y+q2.y+q3.y,
                     q0.z+q1.z+q2.z+q3.z, q0.w+q1.w+q2.w+q3.w };
        ((float4*)partial)[((size_t)b * 64 + c) * 128 + t] = o;
    }
    if (t == 0) partialw[b * 64 + c] = wsums[0] + wsums[1] + wsums[2] + wsums[3];
}

// ---------------------------------------------------------------------------
// K2: per block (dt, b): invS = 1/sum(partialw[b,:]); vbar = invS * float4-
// reduce of partial over 64 chunks; ctx[b, dt*64..+64] = vbar @ Wv + bv.
// ---------------------------------------------------------------------------
__global__ __launch_bounds__(256) void k_ctx(const float* __restrict__ partial,
                                             const float* __restrict__ partialw,
                                             const float* __restrict__ Wv,
                                             const float* __restrict__ bv,
                                             float* __restrict__ ctx)
{
    int dt = blockIdx.x, b = blockIdx.y, t = threadIdx.x;
    __shared__ float4 red4[2][128];
    __shared__ float  vb[512];
    __shared__ float  red[256];
    __shared__ float  invS;

    if (t < 64) {
        float s = partialw[b * 64 + t];
        s += __shfl_xor(s, 1);  s += __shfl_xor(s, 2);
        s += __shfl_xor(s, 4);  s += __shfl_xor(s, 8);
        s += __shfl_xor(s, 16); s += __shfl_xor(s, 32);
        if (t == 0) invS = 1.f / s;
    }
    const int col4 = t & 127, cg = t >> 7;   // cg halves the chunk range
    const float4* pp4 = (const float4*)partial
                      + ((size_t)b * 64 + cg * 32) * 128 + col4;
    float4 a = {0.f, 0.f, 0.f, 0.f};
    #pragma unroll 8
    for (int cc = 0; cc < 32; ++cc) {
        float4 v = pp4[(size_t)cc * 128];
        a.x += v.x; a.y += v.y; a.z += v.z; a.w += v.w;
    }
    red4[cg][col4] = a;
    __syncthreads();                 // red4 + invS visible
    if (t < 128) {
        float4 q0 = red4[0][t], q1 = red4[1][t];
        float is = invS;
        vb[4*t+0] = (q0.x + q1.x) * is;
        vb[4*t+1] = (q0.y + q1.y) * is;
        vb[4*t+2] = (q0.z + q1.z) * is;
        vb[4*t+3] = (q0.w + q1.w) * is;
    }
    __syncthreads();                 // vb visible

    int dl = t & 63, q = t >> 6;
    int d = dt * 64 + dl;
    const float* x  = vb + q * 128;
    const float* Wc = Wv + (size_t)(q * 128) * 512 + d;
    float acc = 0.f;
    #pragma unroll 8
    for (int e = 0; e < 128; ++e) acc = fmaf(x[e], Wc[(size_t)e * 512], acc);
    red[t] = acc; __syncthreads();
    if (t < 64)
        ctx[b * 512 + dt * 64 + t] = red[t] + red[t+64] + red[t+128] + red[t+192]
                                   + bv[dt * 64 + t];
}

// ---------------------------------------------------------------------------
// K3: per block (dt, b): frow[b, dt*64..+64] = ctx[b,:] @ Wo[:, slice] + bo.
// (GEMV done ONCE, not 16x-redundant as before.)
// ---------------------------------------------------------------------------
__global__ __launch_bounds__(256) void k_frow(const float* __restrict__ ctx,
                                              const float* __restrict__ Wo,
                                              const float* __restrict__ bo,
                                              float* __restrict__ frow)
{
    int dt = blockIdx.x, b = blockIdx.y, t = threadIdx.x;
    __shared__ float xs[512];
    __shared__ float red[256];

    xs[t]       = ctx[b * 512 + t];
    xs[t + 256] = ctx[b * 512 + 256 + t];
    __syncthreads();

    int dl = t & 63, q = t >> 6;
    int d = dt * 64 + dl;
    const float* x  = xs + q * 128;
    const float* Wc = Wo + (size_t)(q * 128) * 512 + d;
    float acc = 0.f;
    #pragma unroll 8
    for (int e = 0; e < 128; ++e) acc = fmaf(x[e], Wc[(size_t)e * 512], acc);
    red[t] = acc; __syncthreads();
    if (t < 64)
        frow[b * 512 + dt * 64 + t] = red[t] + red[t+64] + red[t+128] + red[t+192]
                                    + bo[dt * 64 + t];
}

// ---------------------------------------------------------------------------
// K4: pure broadcast. block (s, b) writes rows b*2048+s*32 .. +31 with
// frow[b,:]. Nothing but streaming float4 stores -> write-BW bound.
// ---------------------------------------------------------------------------
__global__ __launch_bounds__(256) void k_bcast(const float* __restrict__ frow,
                                               float* __restrict__ out)
{
    int s = blockIdx.x, b = blockIdx.y, t = threadIdx.x;
    const int col4 = t & 127, h = t >> 7;
    float4 val = ((const float4*)frow)[b * 128 + col4];
    float4* o4 = (float4*)out
               + ((size_t)b * 2048 + s * 32 + h * 16) * 128 + col4;
    #pragma unroll
    for (int r = 0; r < 16; ++r) o4[(size_t)r * 128] = val;
}

extern "C" void kernel_launch(void* const* d_in, const int* in_sizes, int n_in,
                              void* d_out, int out_size, void* d_ws, size_t ws_size,
                              hipStream_t stream) {
    // setup_inputs order: query, key, value, Wq, bq, Wk, bk, Wv, bv, Wo, bo
    const float* key   = (const float*)d_in[1];
    const float* value = (const float*)d_in[2];
    const float* Wk    = (const float*)d_in[5];
    const float* bk    = (const float*)d_in[6];
    const float* Wv    = (const float*)d_in[7];
    const float* bv    = (const float*)d_in[8];
    const float* Wo    = (const float*)d_in[9];
    const float* bo    = (const float*)d_in[10];
    float* out = (float*)d_out;
    float* ws  = (float*)d_ws;

    // workspace layout (floats), ~1.06 MB
    float* partial  = ws;                 // 8*64*512 = 262144
    float* partialw = ws + 262144;        // 512
    float* ctx      = ws + 262656;        // 4096
    float* frow     = ws + 266752;        // 4096

    k_score_wsum<<<dim3(64, 8), 256, 0, stream>>>(key, Wk, bk, value,
                                                  partial, partialw);
    k_ctx <<<dim3(8, 8),  256, 0, stream>>>(partial, partialw, Wv, bv, ctx);
    k_frow<<<dim3(8, 8),  256, 0, stream>>>(ctx, Wo, bo, frow);
    k_bcast<<<dim3(64, 8), 256, 0, stream>>>(frow, out);
}